// Round 4
// baseline (183.315 us; speedup 1.0000x reference)
//
#include <hip/hip_runtime.h>

// Layout constants for activation (32, 16, 224, 224) fp32
#define HW      224
#define PLANE   50176            // 224*224
#define NSTRIDE 802816           // 16*PLANE

// Native 16B vector type usable with __builtin_nontemporal_store
typedef float v4f __attribute__((ext_vector_type(4)));
__device__ __forceinline__ void nt_store4(float* p, float4 v) {
  v4f w; w.x = v.x; w.y = v.y; w.z = v.z; w.w = v.w;
  __builtin_nontemporal_store(w, (v4f*)p);
}

// Work items per section, batched per thread for MLP:
// A: ch 0..3, item = one float4          : 1,605,632 items, 4 items/thread
// B: ch 4..7 (2x2), item = 2x4 region    :   802,816 items, 4 items/thread
// C: ch 8..11 (4x4), item = one block    :   401,408 items, 2 items/thread
// D: ch 12..15 (3x3), LDS strip scheme   :     3,200 workgroups
constexpr int A_ITEMS = 1605632;
constexpr int A_THREADS = A_ITEMS / 4;   // 401,408
constexpr int B_THREADS = 802816 / 4;    // 200,704
constexpr int C_THREADS = 401408 / 2;    // 200,704

constexpr int AB   = A_THREADS / 256;          // 1568 blocks
constexpr int ABC  = AB + B_THREADS / 256;     // 2352
constexpr int ABCD = ABC + C_THREADS / 256;    // 3136
constexpr int TOTAL_BLOCKS = ABCD + 3200;      // 6336

__global__ __launch_bounds__(256) void blockrelu_kernel(
    const float* __restrict__ in, float* __restrict__ out) {
  const int bid = blockIdx.x;
  const int t = threadIdx.x;

  if (bid < AB) {
    // Channels 0..3: 4 independent float4 items per thread, loads grouped first.
    const int t0 = bid * 256 + t;
    long off[4];
    float4 v[4];
    bool relu[4];
    #pragma unroll
    for (int k = 0; k < 4; ++k) {
      int tid = t0 + k * A_THREADS;
      int n = tid / PLANE;
      int r = tid - n * PLANE;
      relu[k] = (r / 12544) >= 2;            // ch 2..3 -> elementwise ReLU
      off[k] = (long)n * NSTRIDE + (long)r * 4;
      v[k] = *(const float4*)(in + off[k]);  // 4 independent loads in flight
    }
    #pragma unroll
    for (int k = 0; k < 4; ++k) {
      float4 w = v[k];
      if (relu[k]) {
        w.x = (w.x >= 0.f) ? w.x : 0.f;
        w.y = (w.y >= 0.f) ? w.y : 0.f;
        w.z = (w.z >= 0.f) ? w.z : 0.f;
        w.w = (w.w >= 0.f) ? w.w : 0.f;
      }
      nt_store4(out + off[k], w);
    }
  } else if (bid < ABC) {
    // 2x2 blocks: 4 independent 2x4 regions per thread (8 loads in flight).
    const int b0 = (bid - AB) * 256 + t;
    long base[4];
    float4 a[4], b[4];
    #pragma unroll
    for (int k = 0; k < 4; ++k) {
      int u = b0 + k * B_THREADS;
      int n = u / 25088;
      int v2 = u - n * 25088;
      int c = 4 + v2 / 6272;
      int w2 = v2 % 6272;
      int brow = w2 / 56;
      int rcol = w2 - brow * 56;
      base[k] = (long)n * NSTRIDE + (long)c * PLANE + (long)(2 * brow) * HW + 4 * rcol;
      a[k] = *(const float4*)(in + base[k]);
      b[k] = *(const float4*)(in + base[k] + HW);
    }
    #pragma unroll
    for (int k = 0; k < 4; ++k) {
      float4 av = a[k], bv = b[k];
      float s0 = ((av.x + av.y) + bv.x) + bv.y;   // row-major order (bit-exact, R1)
      float s1 = ((av.z + av.w) + bv.z) + bv.w;
      if (s0 < 0.f) { av.x = 0.f; av.y = 0.f; bv.x = 0.f; bv.y = 0.f; }
      if (s1 < 0.f) { av.z = 0.f; av.w = 0.f; bv.z = 0.f; bv.w = 0.f; }
      nt_store4(out + base[k], av);
      nt_store4(out + base[k] + HW, bv);
    }
  } else if (bid < ABCD) {
    // 4x4 blocks: 2 independent blocks per thread (8 loads in flight).
    const int c0 = (bid - ABC) * 256 + t;
    long base[2];
    float4 r[2][4];
    #pragma unroll
    for (int k = 0; k < 2; ++k) {
      int u = c0 + k * C_THREADS;
      int n = u / 12544;
      int v2 = u - n * 12544;
      int c = 8 + v2 / 3136;
      int w2 = v2 % 3136;
      int by = w2 / 56;
      int bx = w2 - by * 56;
      base[k] = (long)n * NSTRIDE + (long)c * PLANE + (long)(4 * by) * HW + 4 * bx;
      r[k][0] = *(const float4*)(in + base[k]);
      r[k][1] = *(const float4*)(in + base[k] + HW);
      r[k][2] = *(const float4*)(in + base[k] + 2 * HW);
      r[k][3] = *(const float4*)(in + base[k] + 3 * HW);
    }
    #pragma unroll
    for (int k = 0; k < 2; ++k) {
      float s = r[k][0].x; s += r[k][0].y; s += r[k][0].z; s += r[k][0].w;
      s += r[k][1].x; s += r[k][1].y; s += r[k][1].z; s += r[k][1].w;
      s += r[k][2].x; s += r[k][2].y; s += r[k][2].z; s += r[k][2].w;
      s += r[k][3].x; s += r[k][3].y; s += r[k][3].z; s += r[k][3].w;
      if (s < 0.f) {
        r[k][0] = make_float4(0.f, 0.f, 0.f, 0.f);
        r[k][1] = r[k][0]; r[k][2] = r[k][0]; r[k][3] = r[k][0];
      }
      nt_store4(out + base[k], r[k][0]);
      nt_store4(out + base[k] + HW, r[k][1]);
      nt_store4(out + base[k] + 2 * HW, r[k][2]);
      nt_store4(out + base[k] + 3 * HW, r[k][3]);
    }
  } else {
    // 3x3 blocks via LDS strips (R2 scheme, NT stores added).
    __shared__ float tile[9][228];
    __shared__ float maskL[3][76];
    int wg = bid - ABCD;          // 0..3199
    int p = wg / 25;              // plane 0..127
    int sg = wg - p * 25;         // strip-group 0..24
    int n = p >> 2;
    int c = 12 + (p & 3);
    int h0 = sg * 9;
    int rows = (224 - h0 >= 9) ? 9 : (224 - h0);   // 9, or 8 for sg==24
    long pbase = (long)n * NSTRIDE + (long)c * PLANE;

    for (int i = t; i < 9 * 228; i += 256) ((float*)tile)[i] = 0.f;
    __syncthreads();

    const int nvec = rows * 56;
    for (int idx = t; idx < nvec; idx += 256) {
      int r = idx / 56;
      int q = idx - r * 56;
      float4 v = *(const float4*)(in + pbase + (long)(h0 + r) * HW + q * 4);
      *(float4*)&tile[r][q * 4] = v;
    }
    __syncthreads();

    if (t < 225) {
      int br = t / 75;
      int bx = t - br * 75;
      int r0 = br * 3, cc0 = bx * 3;
      float s = 0.f;
      #pragma unroll
      for (int i = 0; i < 3; ++i)
        #pragma unroll
        for (int j = 0; j < 3; ++j)
          s += tile[r0 + i][cc0 + j];
      maskL[br][bx] = (s >= 0.f) ? 1.f : 0.f;
    }
    __syncthreads();

    for (int idx = t; idx < nvec; idx += 256) {
      int r = idx / 56;
      int q = idx - r * 56;
      int col = q * 4;
      float4 v = *(const float4*)&tile[r][col];
      int br = r / 3;
      v.x *= maskL[br][(col    ) / 3];
      v.y *= maskL[br][(col + 1) / 3];
      v.z *= maskL[br][(col + 2) / 3];
      v.w *= maskL[br][(col + 3) / 3];
      nt_store4(out + pbase + (long)(h0 + r) * HW + col, v);
    }
  }
}

extern "C" void kernel_launch(void* const* d_in, const int* in_sizes, int n_in,
                              void* d_out, int out_size, void* d_ws, size_t ws_size,
                              hipStream_t stream) {
  const float* act = (const float*)d_in[0];
  float* out = (float*)d_out;
  blockrelu_kernel<<<TOTAL_BLOCKS, 256, 0, stream>>>(act, out);
}